// Round 2
// baseline (769.480 us; speedup 1.0000x reference)
//
#include <hip/hip_runtime.h>
#include <hip/hip_bf16.h>
#include <math.h>

typedef __bf16 bf16_t;
typedef __bf16 bf16x8 __attribute__((ext_vector_type(8)));
typedef __bf16 bf16x4 __attribute__((ext_vector_type(4)));
typedef float  f32x4  __attribute__((ext_vector_type(4)));

#define T_ 8
#define B_ 16
#define C_ 256
#define V_ 1024
#define H_ 8
#define D_ 32

#define MFMA __builtin_amdgcn_mfma_f32_16x16x32_bf16

// ---------------------------------------------------------------------------
// Prep: split one f32 256x256 matrix into three bf16 matrices (exact to ~2^-24)
// ---------------------------------------------------------------------------
__global__ __launch_bounds__(256) void k0_split(const float* __restrict__ W,
                                                bf16_t* __restrict__ S0,
                                                bf16_t* __restrict__ S1,
                                                bf16_t* __restrict__ S2)
{
    int i = (blockIdx.x * 256 + threadIdx.x) * 4;
    float4 w = *(const float4*)(W + i);
    float wv[4] = {w.x, w.y, w.z, w.w};
    bf16x4 s0, s1, s2;
#pragma unroll
    for (int j = 0; j < 4; j++) {
        bf16_t a = (bf16_t)wv[j];
        float r1 = wv[j] - (float)a;
        bf16_t b = (bf16_t)r1;
        float r2 = r1 - (float)b;
        bf16_t c = (bf16_t)r2;
        s0[j] = a; s1[j] = b; s2[j] = c;
    }
    *(bf16x4*)(S0 + i) = s0;
    *(bf16x4*)(S1 + i) = s1;
    *(bf16x4*)(S2 + i) = s2;
}

// ---------------------------------------------------------------------------
// Kernel 1: shortcut LIF (tau=2, vth=1, hard reset) + transpose to [T,B,V,C]
// x is float32.
// ---------------------------------------------------------------------------
__global__ __launch_bounds__(256) void k1_lif_tr(const float* __restrict__ x,
                                                 bf16_t* __restrict__ xsT)
{
    __shared__ bf16_t tile[64 * 72];
    const int v0 = blockIdx.x * 64, c0 = blockIdx.y * 64, b = blockIdx.z;
    const int tid = threadIdx.x;
    const int cc = tid >> 2, v16 = (tid & 3) * 16;   // read-phase element set
    const int vr = tid >> 2, c16 = (tid & 3) * 16;   // write-phase element set
    float mem[16];
#pragma unroll
    for (int j = 0; j < 16; j++) mem[j] = 0.0f;

    for (int t = 0; t < T_; t++) {
        const float* xp = x + (((size_t)(t * B_ + b) * C_ + (c0 + cc)) * V_ + v0 + v16);
        float xv[16];
#pragma unroll
        for (int q = 0; q < 4; q++) {
            float4 f = *(const float4*)(xp + q * 4);
            xv[q * 4 + 0] = f.x; xv[q * 4 + 1] = f.y;
            xv[q * 4 + 2] = f.z; xv[q * 4 + 3] = f.w;
        }
#pragma unroll
        for (int j = 0; j < 16; j++) {
            float m = mem[j];
            float d = xv[j] - m;
            m = m + d * 0.5f;                  // v + (x - v)/tau, tau=2 (exact /2)
            float s = (m >= 1.0f) ? 1.0f : 0.0f;
            tile[(v16 + j) * 72 + cc] = (bf16_t)s;
            mem[j] = (s != 0.0f) ? 0.0f : m;
        }
        __syncthreads();
        bf16_t* op = xsT + (((size_t)(t * B_ + b) * V_ + (v0 + vr)) * C_ + c0 + c16);
        *(bf16x8*)op       = *(const bf16x8*)&tile[vr * 72 + c16];
        *(bf16x8*)(op + 8) = *(const bf16x8*)&tile[vr * 72 + c16 + 8];
        __syncthreads();
    }
}

// ---------------------------------------------------------------------------
// Branch GEMM (1x1 conv, triple-bf16-split weights) + BN + LIF fused over T.
// ORIENT=0: out[t,b,o,v] channel-major (A=W, B=xsT)
// ORIENT=1: out[t,b,v,o] v-major       (A=xsT, B=W)
// ---------------------------------------------------------------------------
template <int ORIENT>
__global__ __launch_bounds__(256) void k_branch(const bf16_t* __restrict__ Wsp, // [3][256][256]
                                                const float* __restrict__ bnp,  // [4][256]
                                                const bf16_t* __restrict__ xsT,
                                                bf16_t* __restrict__ outp, float vth)
{
    __shared__ bf16_t Wl[3][64 * 72];
    __shared__ bf16_t Xl[64 * 72];
    __shared__ float bsc[64], bmn[64], bbt[64];
    const int v0 = blockIdx.x * 64, o0 = blockIdx.y * 64, b = blockIdx.z;
    const int tid = threadIdx.x;
    const int w = tid >> 6, l = tid & 63, lq = l >> 4, lr = l & 15;
    const int msub = (w >> 1) * 32, nsub = (w & 1) * 32;

    if (tid < 64) {
        int o = o0 + tid;
        float g = bnp[o], be = bnp[C_ + o];
        float mn = bnp[2 * C_ + o], vr2 = bnp[3 * C_ + o];
        bsc[tid] = g * (1.0f / sqrtf(vr2 + 1e-5f));
        bmn[tid] = mn; bbt[tid] = be;
    }
    float mem[4][4];
#pragma unroll
    for (int st = 0; st < 4; st++)
        for (int r = 0; r < 4; r++) mem[st][r] = 0.0f;

    for (int t = 0; t < T_; t++) {
        f32x4 acc[4];
#pragma unroll
        for (int i = 0; i < 4; i++) acc[i] = (f32x4){0.f, 0.f, 0.f, 0.f};
        for (int kq = 0; kq < 4; kq++) {
            __syncthreads();
#pragma unroll
            for (int i = 0; i < 6; i++) {           // stage W splits: 3*64*64
                int ch = tid + i * 256;
                int lvl = ch >> 9, rem = ch & 511;
                int row = rem >> 3, col8 = (rem & 7) * 8;
                *(bf16x8*)&Wl[lvl][row * 72 + col8] =
                    *(const bf16x8*)&Wsp[lvl * 65536 + (o0 + row) * 256 + kq * 64 + col8];
            }
            {
                size_t xb = ((size_t)(t * B_ + b) * V_ + v0);
#pragma unroll
                for (int i = 0; i < 2; i++) {       // stage X: 64*64
                    int ch = tid + i * 256;
                    int row = ch >> 3, col8 = (ch & 7) * 8;
                    *(bf16x8*)&Xl[row * 72 + col8] =
                        *(const bf16x8*)&xsT[(xb + row) * C_ + kq * 64 + col8];
                }
            }
            __syncthreads();
#pragma unroll
            for (int kk = 0; kk < 2; kk++) {
                int kb = kk * 32 + lq * 8;
                if (ORIENT == 0) {
                    bf16x8 b0 = *(const bf16x8*)&Xl[(nsub + lr) * 72 + kb];
                    bf16x8 b1 = *(const bf16x8*)&Xl[(nsub + 16 + lr) * 72 + kb];
#pragma unroll
                    for (int lvl = 0; lvl < 3; lvl++) {
                        bf16x8 a0 = *(const bf16x8*)&Wl[lvl][(msub + lr) * 72 + kb];
                        bf16x8 a1 = *(const bf16x8*)&Wl[lvl][(msub + 16 + lr) * 72 + kb];
                        acc[0] = MFMA(a0, b0, acc[0], 0, 0, 0);
                        acc[1] = MFMA(a0, b1, acc[1], 0, 0, 0);
                        acc[2] = MFMA(a1, b0, acc[2], 0, 0, 0);
                        acc[3] = MFMA(a1, b1, acc[3], 0, 0, 0);
                    }
                } else {
                    bf16x8 a0 = *(const bf16x8*)&Xl[(msub + lr) * 72 + kb];
                    bf16x8 a1 = *(const bf16x8*)&Xl[(msub + 16 + lr) * 72 + kb];
#pragma unroll
                    for (int lvl = 0; lvl < 3; lvl++) {
                        bf16x8 b0 = *(const bf16x8*)&Wl[lvl][(nsub + lr) * 72 + kb];
                        bf16x8 b1 = *(const bf16x8*)&Wl[lvl][(nsub + 16 + lr) * 72 + kb];
                        acc[0] = MFMA(a0, b0, acc[0], 0, 0, 0);
                        acc[1] = MFMA(a0, b1, acc[1], 0, 0, 0);
                        acc[2] = MFMA(a1, b0, acc[2], 0, 0, 0);
                        acc[3] = MFMA(a1, b1, acc[3], 0, 0, 0);
                    }
                }
            }
        }
        // epilogue: BN + LIF + spike store
#pragma unroll
        for (int st = 0; st < 4; st++) {
            int mi = st >> 1, ni = st & 1;
#pragma unroll
            for (int r = 0; r < 4; r++) {
                int m = msub + mi * 16 + lq * 4 + r;
                int n = nsub + ni * 16 + lr;
                int ol = ORIENT ? n : m;
                int vl = ORIENT ? m : n;
                float y = (acc[st][r] - bmn[ol]) * bsc[ol] + bbt[ol];
                float mm = mem[st][r];
                mm = mm + (y - mm) * 0.5f;
                float s = (mm >= vth) ? 1.0f : 0.0f;
                size_t idx = ORIENT
                    ? (((size_t)(t * B_ + b) * V_ + (v0 + vl)) * C_ + (o0 + ol))
                    : (((size_t)(t * B_ + b) * C_ + (o0 + ol)) * V_ + (v0 + vl));
                outp[idx] = (bf16_t)s;
                mem[st][r] = (s != 0.0f) ? 0.0f : mm;
            }
        }
    }
}

// ---------------------------------------------------------------------------
// attn^T[e][d] = (1/N) * sum_{t in chunk, n} v[e,n] * k[d,n] (exact integers),
// stored as exact hi/lo bf16 split (attn = integer/1024, <= 2048/1024).
// ---------------------------------------------------------------------------
__global__ __launch_bounds__(64) void k_attn(const bf16_t* __restrict__ vc,
                                             const bf16_t* __restrict__ kc,
                                             bf16_t* __restrict__ ahi,
                                             bf16_t* __restrict__ alo)
{
    const int fid = blockIdx.x;                 // ((nc*16+b)*8+h)
    const int h = fid & 7, b = (fid >> 3) & 15, nc = fid >> 7;
    const int l = threadIdx.x, lq = l >> 4, lr = l & 15;
    f32x4 acc[4];
#pragma unroll
    for (int i = 0; i < 4; i++) acc[i] = (f32x4){0.f, 0.f, 0.f, 0.f};
    for (int s = 0; s < 64; s++) {
        int t = nc * 2 + (s >> 5);
        int n0 = (s & 31) * 32;
        size_t rb = ((size_t)(t * B_ + b) * C_ + h * D_ + lr) * V_ + n0 + lq * 8;
        bf16x8 a0 = *(const bf16x8*)&vc[rb];
        bf16x8 a1 = *(const bf16x8*)&vc[rb + (size_t)16 * V_];
        bf16x8 b0 = *(const bf16x8*)&kc[rb];
        bf16x8 b1 = *(const bf16x8*)&kc[rb + (size_t)16 * V_];
        acc[0] = MFMA(a0, b0, acc[0], 0, 0, 0);
        acc[1] = MFMA(a0, b1, acc[1], 0, 0, 0);
        acc[2] = MFMA(a1, b0, acc[2], 0, 0, 0);
        acc[3] = MFMA(a1, b1, acc[3], 0, 0, 0);
    }
    size_t ob = (size_t)fid * 1024;
#pragma unroll
    for (int st = 0; st < 4; st++) {
        int ei = st >> 1, di = st & 1;
#pragma unroll
        for (int r = 0; r < 4; r++) {
            int e = ei * 16 + lq * 4 + r;
            int d = di * 16 + lr;
            float val = acc[st][r] * (1.0f / 1024.0f);   // exact dyadic
            bf16_t hi = (bf16_t)val;
            float lo = val - (float)hi;                  // exact residual
            ahi[ob + e * 32 + d] = hi;
            alo[ob + e * 32 + d] = (bf16_t)lo;           // exact (few bits)
        }
    }
}

// ---------------------------------------------------------------------------
// y2 = q . attn (exact hi/lo double-MFMA), fused attn_lif (vth=0.5, exact)
// -> spikes y3T v-major [T,B,V,C]
// ---------------------------------------------------------------------------
__global__ __launch_bounds__(256) void k_attn_out(const bf16_t* __restrict__ qT,
                                                  const bf16_t* __restrict__ ahi,
                                                  const bf16_t* __restrict__ alo,
                                                  bf16_t* __restrict__ y3T)
{
    const int tid = threadIdx.x, w = tid >> 6, l = tid & 63, lq = l >> 4, lr = l & 15;
    const int n0 = blockIdx.x * 64 + (w >> 1) * 32;
    const int h = blockIdx.y * 2 + (w & 1);
    const int b = blockIdx.z;
    float mem[4][4];
#pragma unroll
    for (int st = 0; st < 4; st++)
        for (int r = 0; r < 4; r++) mem[st][r] = 0.0f;

    for (int t = 0; t < T_; t++) {
        int nc = t >> 1;
        const bf16_t* qp = qT + ((size_t)(t * B_ + b) * V_ + n0 + lr) * C_ + h * D_ + lq * 8;
        bf16x8 a0 = *(const bf16x8*)qp;
        bf16x8 a1 = *(const bf16x8*)(qp + 16 * C_);
        size_t ab = ((size_t)(nc * B_ + b) * H_ + h) * 1024;
        bf16x8 bh0 = *(const bf16x8*)&ahi[ab + lr * 32 + lq * 8];
        bf16x8 bh1 = *(const bf16x8*)&ahi[ab + (16 + lr) * 32 + lq * 8];
        bf16x8 bl0 = *(const bf16x8*)&alo[ab + lr * 32 + lq * 8];
        bf16x8 bl1 = *(const bf16x8*)&alo[ab + (16 + lr) * 32 + lq * 8];
#pragma unroll
        for (int st = 0; st < 4; st++) {
            int mi = st >> 1, ni = st & 1;
            f32x4 z = (f32x4){0.f, 0.f, 0.f, 0.f};
            z = MFMA(mi ? a1 : a0, ni ? bh1 : bh0, z, 0, 0, 0);
            z = MFMA(mi ? a1 : a0, ni ? bl1 : bl0, z, 0, 0, 0);
#pragma unroll
            for (int r = 0; r < 4; r++) {
                int n = n0 + mi * 16 + lq * 4 + r;
                int e = ni * 16 + lr;
                float mm = mem[st][r];
                mm = mm + (z[r] - mm) * 0.5f;   // exact dyadic
                float s = (mm >= 0.5f) ? 1.0f : 0.0f;
                y3T[((size_t)(t * B_ + b) * V_ + n) * C_ + h * D_ + e] = (bf16_t)s;
                mem[st][r] = (s != 0.0f) ? 0.0f : mm;
            }
        }
    }
}

// ---------------------------------------------------------------------------
// proj GEMM (triple split) + bias + BN + identity add -> out0 f32 [T,B,C,V]
// ---------------------------------------------------------------------------
__global__ __launch_bounds__(256) void k_proj(const bf16_t* __restrict__ Wsp,
                                              const float* __restrict__ pb,
                                              const float* __restrict__ bnp,
                                              const bf16_t* __restrict__ y3T,
                                              const float* __restrict__ x,
                                              float* __restrict__ out0)
{
    __shared__ bf16_t Wl[3][64 * 72];
    __shared__ bf16_t Xl[64 * 72];
    __shared__ float bsc[64], bmn[64], bbt[64], bbi[64];
    const int v0 = blockIdx.x * 64, o0 = blockIdx.y * 64;
    const int tb = blockIdx.z, t = tb >> 4, b = tb & 15;
    const int tid = threadIdx.x, w = tid >> 6, l = tid & 63, lq = l >> 4, lr = l & 15;
    const int msub = (w >> 1) * 32, nsub = (w & 1) * 32;

    if (tid < 64) {
        int o = o0 + tid;
        float g = bnp[o], be = bnp[C_ + o];
        float mn = bnp[2 * C_ + o], vr2 = bnp[3 * C_ + o];
        bsc[tid] = g * (1.0f / sqrtf(vr2 + 1e-5f));
        bmn[tid] = mn; bbt[tid] = be; bbi[tid] = pb[o];
    }
    f32x4 acc[4];
#pragma unroll
    for (int i = 0; i < 4; i++) acc[i] = (f32x4){0.f, 0.f, 0.f, 0.f};
    for (int kq = 0; kq < 4; kq++) {
        __syncthreads();
#pragma unroll
        for (int i = 0; i < 6; i++) {
            int ch = tid + i * 256;
            int lvl = ch >> 9, rem = ch & 511;
            int row = rem >> 3, col8 = (rem & 7) * 8;
            *(bf16x8*)&Wl[lvl][row * 72 + col8] =
                *(const bf16x8*)&Wsp[lvl * 65536 + (o0 + row) * 256 + kq * 64 + col8];
        }
        {
            size_t xb = ((size_t)(t * B_ + b) * V_ + v0);
#pragma unroll
            for (int i = 0; i < 2; i++) {
                int ch = tid + i * 256;
                int row = ch >> 3, col8 = (ch & 7) * 8;
                *(bf16x8*)&Xl[row * 72 + col8] =
                    *(const bf16x8*)&y3T[(xb + row) * C_ + kq * 64 + col8];
            }
        }
        __syncthreads();
#pragma unroll
        for (int kk = 0; kk < 2; kk++) {
            int kb = kk * 32 + lq * 8;
            bf16x8 b0 = *(const bf16x8*)&Xl[(nsub + lr) * 72 + kb];
            bf16x8 b1 = *(const bf16x8*)&Xl[(nsub + 16 + lr) * 72 + kb];
#pragma unroll
            for (int lvl = 0; lvl < 3; lvl++) {
                bf16x8 a0 = *(const bf16x8*)&Wl[lvl][(msub + lr) * 72 + kb];
                bf16x8 a1 = *(const bf16x8*)&Wl[lvl][(msub + 16 + lr) * 72 + kb];
                acc[0] = MFMA(a0, b0, acc[0], 0, 0, 0);
                acc[1] = MFMA(a0, b1, acc[1], 0, 0, 0);
                acc[2] = MFMA(a1, b0, acc[2], 0, 0, 0);
                acc[3] = MFMA(a1, b1, acc[3], 0, 0, 0);
            }
        }
    }
#pragma unroll
    for (int st = 0; st < 4; st++) {
        int mi = st >> 1, ni = st & 1;
#pragma unroll
        for (int r = 0; r < 4; r++) {
            int m = msub + mi * 16 + lq * 4 + r;
            int n = nsub + ni * 16 + lr;
            size_t idx = ((size_t)(t * B_ + b) * C_ + (o0 + m)) * V_ + (v0 + n);
            float y = acc[st][r] + bbi[m];
            y = (y - bmn[m]) * bsc[m] + bbt[m];
            y += x[idx];
            out0[idx] = y;
        }
    }
}

// ---------------------------------------------------------------------------
// output 1: v spikes [T,B,C,V] -> f32 [T,B,H,N,D] (per-head 32x1024 transpose)
// ---------------------------------------------------------------------------
__global__ __launch_bounds__(256) void k_vout(const bf16_t* __restrict__ vc,
                                              float* __restrict__ out1)
{
    __shared__ bf16_t tl[32 * 136];
    const int n0 = blockIdx.x * 128;
    const int f = blockIdx.y;                 // (t*16+b)*8+h
    const int tb = f >> 3, h = f & 7;
    const int tid = threadIdx.x;
    {
        int d = tid >> 3, nn = (tid & 7) * 16;
        const bf16_t* vp = vc + ((size_t)tb * C_ + h * D_ + d) * V_ + n0 + nn;
        *(bf16x8*)&tl[d * 136 + nn]     = *(const bf16x8*)vp;
        *(bf16x8*)&tl[d * 136 + nn + 8] = *(const bf16x8*)(vp + 8);
    }
    __syncthreads();
    {
        int n = tid >> 1, d16 = (tid & 1) * 16;
        float* op = out1 + (size_t)f * (V_ * D_) + (size_t)(n0 + n) * D_ + d16;
#pragma unroll
        for (int q = 0; q < 4; q++) {
            float4 o;
            o.x = (float)tl[(d16 + q * 4 + 0) * 136 + n];
            o.y = (float)tl[(d16 + q * 4 + 1) * 136 + n];
            o.z = (float)tl[(d16 + q * 4 + 2) * 136 + n];
            o.w = (float)tl[(d16 + q * 4 + 3) * 136 + n];
            *(float4*)(op + q * 4) = o;
        }
    }
}

// ---------------------------------------------------------------------------
extern "C" void kernel_launch(void* const* d_in, const int* in_sizes, int n_in,
                              void* d_out, int out_size, void* d_ws, size_t ws_size,
                              hipStream_t stream)
{
    const float* x    = (const float*)d_in[0];
    const float* q_w  = (const float*)d_in[1];
    const float* k_w  = (const float*)d_in[2];
    const float* v_w  = (const float*)d_in[3];
    const float* pw   = (const float*)d_in[4];
    const float* pb   = (const float*)d_in[5];
    const float* bn_q = (const float*)d_in[6];
    const float* bn_k = (const float*)d_in[7];
    const float* bn_v = (const float*)d_in[8];
    const float* bn_p = (const float*)d_in[9];

    char* ws = (char*)d_ws;
    bf16_t* xsT  = (bf16_t*)(ws);                                 // 64 MiB (reused as y3T)
    bf16_t* vc   = (bf16_t*)(ws + ((size_t)64 << 20));            // 64 MiB
    bf16_t* ahi  = (bf16_t*)(ws + ((size_t)128 << 20));           // 1 MiB
    bf16_t* alo  = (bf16_t*)(ws + ((size_t)129 << 20));           // 1 MiB
    bf16_t* wspq = (bf16_t*)(ws + ((size_t)130 << 20));           // 4 x 384 KiB
    bf16_t* wspk = wspq + 3 * 65536;
    bf16_t* wspv = wspk + 3 * 65536;
    bf16_t* wspp = wspv + 3 * 65536;
    bf16_t* y3T  = xsT;                                           // reuse after v-branch

    float* outf = (float*)d_out;
    bf16_t* qT = (bf16_t*)d_out;                                  // scratch in out0 half
    bf16_t* kc = (bf16_t*)((char*)d_out + ((size_t)64 << 20));    // scratch in out0 half

    k0_split<<<dim3(64), 256, 0, stream>>>(q_w, wspq, wspq + 65536, wspq + 131072);
    k0_split<<<dim3(64), 256, 0, stream>>>(k_w, wspk, wspk + 65536, wspk + 131072);
    k0_split<<<dim3(64), 256, 0, stream>>>(v_w, wspv, wspv + 65536, wspv + 131072);
    k0_split<<<dim3(64), 256, 0, stream>>>(pw,  wspp, wspp + 65536, wspp + 131072);

    k1_lif_tr   <<<dim3(16, 4, 16),  256, 0, stream>>>(x, xsT);
    k_branch<1> <<<dim3(16, 4, 16),  256, 0, stream>>>(wspq, bn_q, xsT, qT, 1.0f);
    k_branch<0> <<<dim3(16, 4, 16),  256, 0, stream>>>(wspk, bn_k, xsT, kc, 1.0f);
    k_branch<0> <<<dim3(16, 4, 16),  256, 0, stream>>>(wspv, bn_v, xsT, vc, 1.0f);
    k_attn      <<<dim3(512),         64, 0, stream>>>(vc, kc, ahi, alo);
    k_attn_out  <<<dim3(16, 4, 16),  256, 0, stream>>>(qT, ahi, alo, y3T);
    k_proj      <<<dim3(16, 4, 128), 256, 0, stream>>>(wspp, pb, bn_p, y3T, x, outf);
    k_vout      <<<dim3(8, 1024),    256, 0, stream>>>(vc, outf + (size_t)33554432);
}

// Round 3
// 712.571 us; speedup vs baseline: 1.0799x; 1.0799x over previous
//
#include <hip/hip_runtime.h>
#include <hip/hip_bf16.h>
#include <math.h>

typedef __bf16 bf16_t;
typedef __bf16 bf16x8 __attribute__((ext_vector_type(8)));
typedef __bf16 bf16x4 __attribute__((ext_vector_type(4)));
typedef float  f32x4  __attribute__((ext_vector_type(4)));

#define T_ 8
#define B_ 16
#define C_ 256
#define V_ 1024
#define H_ 8
#define D_ 32

#define MFMA __builtin_amdgcn_mfma_f32_16x16x32_bf16

// ---------------------------------------------------------------------------
// Prep: split one f32 256x256 matrix into three bf16 matrices (exact to ~2^-24)
// ---------------------------------------------------------------------------
__global__ __launch_bounds__(256) void k0_split(const float* __restrict__ W,
                                                bf16_t* __restrict__ S0,
                                                bf16_t* __restrict__ S1,
                                                bf16_t* __restrict__ S2)
{
    int i = (blockIdx.x * 256 + threadIdx.x) * 4;
    float4 w = *(const float4*)(W + i);
    float wv[4] = {w.x, w.y, w.z, w.w};
    bf16x4 s0, s1, s2;
#pragma unroll
    for (int j = 0; j < 4; j++) {
        bf16_t a = (bf16_t)wv[j];
        float r1 = wv[j] - (float)a;
        bf16_t b = (bf16_t)r1;
        float r2 = r1 - (float)b;
        bf16_t c = (bf16_t)r2;
        s0[j] = a; s1[j] = b; s2[j] = c;
    }
    *(bf16x4*)(S0 + i) = s0;
    *(bf16x4*)(S1 + i) = s1;
    *(bf16x4*)(S2 + i) = s2;
}

// ---------------------------------------------------------------------------
// Kernel 1: shortcut LIF (tau=2, vth=1, hard reset) + transpose to [T,B,V,C]
// ---------------------------------------------------------------------------
__global__ __launch_bounds__(256) void k1_lif_tr(const float* __restrict__ x,
                                                 bf16_t* __restrict__ xsT)
{
    __shared__ bf16_t tile[64 * 72];
    const int v0 = blockIdx.x * 64, c0 = blockIdx.y * 64, b = blockIdx.z;
    const int tid = threadIdx.x;
    const int cc = tid >> 2, v16 = (tid & 3) * 16;
    const int vr = tid >> 2, c16 = (tid & 3) * 16;
    float mem[16];
#pragma unroll
    for (int j = 0; j < 16; j++) mem[j] = 0.0f;

    for (int t = 0; t < T_; t++) {
        const float* xp = x + (((size_t)(t * B_ + b) * C_ + (c0 + cc)) * V_ + v0 + v16);
        float xv[16];
#pragma unroll
        for (int q = 0; q < 4; q++) {
            float4 f = *(const float4*)(xp + q * 4);
            xv[q * 4 + 0] = f.x; xv[q * 4 + 1] = f.y;
            xv[q * 4 + 2] = f.z; xv[q * 4 + 3] = f.w;
        }
#pragma unroll
        for (int j = 0; j < 16; j++) {
            float m = mem[j];
            float d = xv[j] - m;
            m = m + d * 0.5f;
            float s = (m >= 1.0f) ? 1.0f : 0.0f;
            tile[(v16 + j) * 72 + cc] = (bf16_t)s;
            mem[j] = (s != 0.0f) ? 0.0f : m;
        }
        __syncthreads();
        bf16_t* op = xsT + (((size_t)(t * B_ + b) * V_ + (v0 + vr)) * C_ + c0 + c16);
        *(bf16x8*)op       = *(const bf16x8*)&tile[vr * 72 + c16];
        *(bf16x8*)(op + 8) = *(const bf16x8*)&tile[vr * 72 + c16 + 8];
        __syncthreads();
    }
}

// ---------------------------------------------------------------------------
// Branch GEMM (1x1 conv, triple-bf16-split weights) + BN + LIF fused over T.
// kq-outer / acc[8t] structure: W k-chunk staged ONCE per block per kq,
// X chunk staged for all 8 t; MFMA:DS-instr ratio ~3:1.
// ORIENT=0: out[t,b,o,v] channel-major; ORIENT=1: out[t,b,v,o] v-major.
// A=W (m=o), B=X (n=v) in both cases; only the store indexing differs.
// ---------------------------------------------------------------------------
template <int ORIENT>
__global__ __launch_bounds__(256, 2) void k_branch(const bf16_t* __restrict__ Wsp, // [3][256][256]
                                                   const float* __restrict__ bnp,  // [4][256]
                                                   const bf16_t* __restrict__ xsT,
                                                   bf16_t* __restrict__ outp, float vth)
{
    __shared__ bf16_t Wl[3][64 * 40];   // stride 40: 2-way bank alias only (free)
    __shared__ bf16_t Xl[8][64 * 40];
    __shared__ float bsc[64], bmn[64], bbt[64];
    const int v0 = blockIdx.x * 64, o0 = blockIdx.y * 64, b = blockIdx.z;
    const int tid = threadIdx.x;
    const int w = tid >> 6, l = tid & 63, lq = l >> 4, lr = l & 15;
    const int msub = (w >> 1) * 32, nsub = (w & 1) * 32;

    if (tid < 64) {
        int o = o0 + tid;
        float g = bnp[o], be = bnp[C_ + o];
        float mn = bnp[2 * C_ + o], vr2 = bnp[3 * C_ + o];
        bsc[tid] = g * (1.0f / sqrtf(vr2 + 1e-5f));
        bmn[tid] = mn; bbt[tid] = be;
    }

    f32x4 acc[8][4];
#pragma unroll
    for (int t = 0; t < 8; t++)
#pragma unroll
        for (int i = 0; i < 4; i++) acc[t][i] = (f32x4){0.f, 0.f, 0.f, 0.f};

    for (int kq = 0; kq < 8; kq++) {
        __syncthreads();
#pragma unroll
        for (int i = 0; i < 3; i++) {               // stage W chunk: 3*64*32
            int ch = tid + i * 256;
            int lvl = ch >> 8, rem = ch & 255;
            int row = rem >> 2, col8 = (rem & 3) * 8;
            *(bf16x8*)&Wl[lvl][row * 40 + col8] =
                *(const bf16x8*)&Wsp[lvl * 65536 + (o0 + row) * 256 + kq * 32 + col8];
        }
#pragma unroll
        for (int i = 0; i < 8; i++) {               // stage X chunk: 8t*64v*32k
            int ch = tid + i * 256;
            int tt = ch >> 8, rem = ch & 255;
            int row = rem >> 2, col8 = (rem & 3) * 8;
            *(bf16x8*)&Xl[tt][row * 40 + col8] =
                *(const bf16x8*)&xsT[((size_t)(tt * B_ + b) * V_ + v0 + row) * C_ + kq * 32 + col8];
        }
        __syncthreads();

        bf16x8 aw0[3], aw1[3];
#pragma unroll
        for (int lvl = 0; lvl < 3; lvl++) {
            aw0[lvl] = *(const bf16x8*)&Wl[lvl][(msub + lr) * 40 + lq * 8];
            aw1[lvl] = *(const bf16x8*)&Wl[lvl][(msub + 16 + lr) * 40 + lq * 8];
        }
#pragma unroll
        for (int t = 0; t < 8; t++) {
            bf16x8 b0 = *(const bf16x8*)&Xl[t][(nsub + lr) * 40 + lq * 8];
            bf16x8 b1 = *(const bf16x8*)&Xl[t][(nsub + 16 + lr) * 40 + lq * 8];
#pragma unroll
            for (int lvl = 0; lvl < 3; lvl++) {     // same chain order as round 2
                acc[t][0] = MFMA(aw0[lvl], b0, acc[t][0], 0, 0, 0);
                acc[t][1] = MFMA(aw0[lvl], b1, acc[t][1], 0, 0, 0);
                acc[t][2] = MFMA(aw1[lvl], b0, acc[t][2], 0, 0, 0);
                acc[t][3] = MFMA(aw1[lvl], b1, acc[t][3], 0, 0, 0);
            }
        }
    }

    // epilogue: BN + LIF recurrence over t + spike store
    float mem[4][4];
#pragma unroll
    for (int st = 0; st < 4; st++)
#pragma unroll
        for (int r = 0; r < 4; r++) mem[st][r] = 0.0f;
#pragma unroll
    for (int t = 0; t < 8; t++) {
#pragma unroll
        for (int st = 0; st < 4; st++) {
            int mi = st >> 1, ni = st & 1;
#pragma unroll
            for (int r = 0; r < 4; r++) {
                int m = msub + mi * 16 + lq * 4 + r;
                int n = nsub + ni * 16 + lr;
                float y = (acc[t][st][r] - bmn[m]) * bsc[m] + bbt[m];
                float mm = mem[st][r];
                mm = mm + (y - mm) * 0.5f;
                float s = (mm >= vth) ? 1.0f : 0.0f;
                size_t idx = ORIENT
                    ? (((size_t)(t * B_ + b) * V_ + (v0 + n)) * C_ + (o0 + m))
                    : (((size_t)(t * B_ + b) * C_ + (o0 + m)) * V_ + (v0 + n));
                outp[idx] = (bf16_t)s;
                mem[st][r] = (s != 0.0f) ? 0.0f : mm;
            }
        }
    }
}

// ---------------------------------------------------------------------------
// attn^T[e][d] = (1/N) * sum_{t in chunk, n} v[e,n] * k[d,n] (exact integers),
// stored as exact hi/lo bf16 split.
// ---------------------------------------------------------------------------
__global__ __launch_bounds__(64) void k_attn(const bf16_t* __restrict__ vc,
                                             const bf16_t* __restrict__ kc,
                                             bf16_t* __restrict__ ahi,
                                             bf16_t* __restrict__ alo)
{
    const int fid = blockIdx.x;                 // ((nc*16+b)*8+h)
    const int h = fid & 7, b = (fid >> 3) & 15, nc = fid >> 7;
    const int l = threadIdx.x, lq = l >> 4, lr = l & 15;
    f32x4 acc[4];
#pragma unroll
    for (int i = 0; i < 4; i++) acc[i] = (f32x4){0.f, 0.f, 0.f, 0.f};
    for (int s = 0; s < 64; s++) {
        int t = nc * 2 + (s >> 5);
        int n0 = (s & 31) * 32;
        size_t rb = ((size_t)(t * B_ + b) * C_ + h * D_ + lr) * V_ + n0 + lq * 8;
        bf16x8 a0 = *(const bf16x8*)&vc[rb];
        bf16x8 a1 = *(const bf16x8*)&vc[rb + (size_t)16 * V_];
        bf16x8 b0 = *(const bf16x8*)&kc[rb];
        bf16x8 b1 = *(const bf16x8*)&kc[rb + (size_t)16 * V_];
        acc[0] = MFMA(a0, b0, acc[0], 0, 0, 0);
        acc[1] = MFMA(a0, b1, acc[1], 0, 0, 0);
        acc[2] = MFMA(a1, b0, acc[2], 0, 0, 0);
        acc[3] = MFMA(a1, b1, acc[3], 0, 0, 0);
    }
    size_t ob = (size_t)fid * 1024;
#pragma unroll
    for (int st = 0; st < 4; st++) {
        int ei = st >> 1, di = st & 1;
#pragma unroll
        for (int r = 0; r < 4; r++) {
            int e = ei * 16 + lq * 4 + r;
            int d = di * 16 + lr;
            float val = acc[st][r] * (1.0f / 1024.0f);   // exact dyadic
            bf16_t hi = (bf16_t)val;
            float lo = val - (float)hi;                  // exact residual
            ahi[ob + e * 32 + d] = hi;
            alo[ob + e * 32 + d] = (bf16_t)lo;
        }
    }
}

// ---------------------------------------------------------------------------
// y2 = q . attn (exact hi/lo double-MFMA), fused attn_lif (vth=0.5, exact)
// -> spikes y3T v-major [T,B,V,C]
// ---------------------------------------------------------------------------
__global__ __launch_bounds__(256) void k_attn_out(const bf16_t* __restrict__ qT,
                                                  const bf16_t* __restrict__ ahi,
                                                  const bf16_t* __restrict__ alo,
                                                  bf16_t* __restrict__ y3T)
{
    const int tid = threadIdx.x, w = tid >> 6, l = tid & 63, lq = l >> 4, lr = l & 15;
    const int n0 = blockIdx.x * 64 + (w >> 1) * 32;
    const int h = blockIdx.y * 2 + (w & 1);
    const int b = blockIdx.z;
    float mem[4][4];
#pragma unroll
    for (int st = 0; st < 4; st++)
#pragma unroll
        for (int r = 0; r < 4; r++) mem[st][r] = 0.0f;

    for (int t = 0; t < T_; t++) {
        int nc = t >> 1;
        const bf16_t* qp = qT + ((size_t)(t * B_ + b) * V_ + n0 + lr) * C_ + h * D_ + lq * 8;
        bf16x8 a0 = *(const bf16x8*)qp;
        bf16x8 a1 = *(const bf16x8*)(qp + 16 * C_);
        size_t ab = ((size_t)(nc * B_ + b) * H_ + h) * 1024;
        bf16x8 bh0 = *(const bf16x8*)&ahi[ab + lr * 32 + lq * 8];
        bf16x8 bh1 = *(const bf16x8*)&ahi[ab + (16 + lr) * 32 + lq * 8];
        bf16x8 bl0 = *(const bf16x8*)&alo[ab + lr * 32 + lq * 8];
        bf16x8 bl1 = *(const bf16x8*)&alo[ab + (16 + lr) * 32 + lq * 8];
#pragma unroll
        for (int st = 0; st < 4; st++) {
            int mi = st >> 1, ni = st & 1;
            f32x4 z = (f32x4){0.f, 0.f, 0.f, 0.f};
            z = MFMA(mi ? a1 : a0, ni ? bh1 : bh0, z, 0, 0, 0);
            z = MFMA(mi ? a1 : a0, ni ? bl1 : bl0, z, 0, 0, 0);
#pragma unroll
            for (int r = 0; r < 4; r++) {
                int n = n0 + mi * 16 + lq * 4 + r;
                int e = ni * 16 + lr;
                float mm = mem[st][r];
                mm = mm + (z[r] - mm) * 0.5f;
                float s = (mm >= 0.5f) ? 1.0f : 0.0f;
                y3T[((size_t)(t * B_ + b) * V_ + n) * C_ + h * D_ + e] = (bf16_t)s;
                mem[st][r] = (s != 0.0f) ? 0.0f : mm;
            }
        }
    }
}

// ---------------------------------------------------------------------------
// proj GEMM (triple split, kq-outer/acc[8t]) + bias + BN + identity -> f32
// ---------------------------------------------------------------------------
__global__ __launch_bounds__(256, 2) void k_proj(const bf16_t* __restrict__ Wsp,
                                                 const float* __restrict__ pb,
                                                 const float* __restrict__ bnp,
                                                 const bf16_t* __restrict__ y3T,
                                                 const float* __restrict__ x,
                                                 float* __restrict__ out0)
{
    __shared__ bf16_t Wl[3][64 * 40];
    __shared__ bf16_t Xl[8][64 * 40];
    __shared__ float bsc[64], bmn[64], bbt[64], bbi[64];
    const int v0 = blockIdx.x * 64, o0 = blockIdx.y * 64, b = blockIdx.z;
    const int tid = threadIdx.x;
    const int w = tid >> 6, l = tid & 63, lq = l >> 4, lr = l & 15;
    const int msub = (w >> 1) * 32, nsub = (w & 1) * 32;

    if (tid < 64) {
        int o = o0 + tid;
        float g = bnp[o], be = bnp[C_ + o];
        float mn = bnp[2 * C_ + o], vr2 = bnp[3 * C_ + o];
        bsc[tid] = g * (1.0f / sqrtf(vr2 + 1e-5f));
        bmn[tid] = mn; bbt[tid] = be; bbi[tid] = pb[o];
    }

    f32x4 acc[8][4];
#pragma unroll
    for (int t = 0; t < 8; t++)
#pragma unroll
        for (int i = 0; i < 4; i++) acc[t][i] = (f32x4){0.f, 0.f, 0.f, 0.f};

    for (int kq = 0; kq < 8; kq++) {
        __syncthreads();
#pragma unroll
        for (int i = 0; i < 3; i++) {
            int ch = tid + i * 256;
            int lvl = ch >> 8, rem = ch & 255;
            int row = rem >> 2, col8 = (rem & 3) * 8;
            *(bf16x8*)&Wl[lvl][row * 40 + col8] =
                *(const bf16x8*)&Wsp[lvl * 65536 + (o0 + row) * 256 + kq * 32 + col8];
        }
#pragma unroll
        for (int i = 0; i < 8; i++) {
            int ch = tid + i * 256;
            int tt = ch >> 8, rem = ch & 255;
            int row = rem >> 2, col8 = (rem & 3) * 8;
            *(bf16x8*)&Xl[tt][row * 40 + col8] =
                *(const bf16x8*)&y3T[((size_t)(tt * B_ + b) * V_ + v0 + row) * C_ + kq * 32 + col8];
        }
        __syncthreads();

        bf16x8 aw0[3], aw1[3];
#pragma unroll
        for (int lvl = 0; lvl < 3; lvl++) {
            aw0[lvl] = *(const bf16x8*)&Wl[lvl][(msub + lr) * 40 + lq * 8];
            aw1[lvl] = *(const bf16x8*)&Wl[lvl][(msub + 16 + lr) * 40 + lq * 8];
        }
#pragma unroll
        for (int t = 0; t < 8; t++) {
            bf16x8 b0 = *(const bf16x8*)&Xl[t][(nsub + lr) * 40 + lq * 8];
            bf16x8 b1 = *(const bf16x8*)&Xl[t][(nsub + 16 + lr) * 40 + lq * 8];
#pragma unroll
            for (int lvl = 0; lvl < 3; lvl++) {
                acc[t][0] = MFMA(aw0[lvl], b0, acc[t][0], 0, 0, 0);
                acc[t][1] = MFMA(aw0[lvl], b1, acc[t][1], 0, 0, 0);
                acc[t][2] = MFMA(aw1[lvl], b0, acc[t][2], 0, 0, 0);
                acc[t][3] = MFMA(aw1[lvl], b1, acc[t][3], 0, 0, 0);
            }
        }
    }

#pragma unroll
    for (int t = 0; t < 8; t++) {
#pragma unroll
        for (int st = 0; st < 4; st++) {
            int mi = st >> 1, ni = st & 1;
#pragma unroll
            for (int r = 0; r < 4; r++) {
                int m = msub + mi * 16 + lq * 4 + r;
                int n = nsub + ni * 16 + lr;
                size_t idx = ((size_t)(t * B_ + b) * C_ + (o0 + m)) * V_ + (v0 + n);
                float y = acc[t][st][r] + bbi[m];
                y = (y - bmn[m]) * bsc[m] + bbt[m];
                y += x[idx];
                out0[idx] = y;
            }
        }
    }
}

// ---------------------------------------------------------------------------
// output 1: v spikes [T,B,C,V] -> f32 [T,B,H,N,D]
// ---------------------------------------------------------------------------
__global__ __launch_bounds__(256) void k_vout(const bf16_t* __restrict__ vc,
                                              float* __restrict__ out1)
{
    __shared__ bf16_t tl[32 * 136];
    const int n0 = blockIdx.x * 128;
    const int f = blockIdx.y;                 // (t*16+b)*8+h
    const int tb = f >> 3, h = f & 7;
    const int tid = threadIdx.x;
    {
        int d = tid >> 3, nn = (tid & 7) * 16;
        const bf16_t* vp = vc + ((size_t)tb * C_ + h * D_ + d) * V_ + n0 + nn;
        *(bf16x8*)&tl[d * 136 + nn]     = *(const bf16x8*)vp;
        *(bf16x8*)&tl[d * 136 + nn + 8] = *(const bf16x8*)(vp + 8);
    }
    __syncthreads();
    {
        int n = tid >> 1, d16 = (tid & 1) * 16;
        float* op = out1 + (size_t)f * (V_ * D_) + (size_t)(n0 + n) * D_ + d16;
#pragma unroll
        for (int q = 0; q < 4; q++) {
            float4 o;
            o.x = (float)tl[(d16 + q * 4 + 0) * 136 + n];
            o.y = (float)tl[(d16 + q * 4 + 1) * 136 + n];
            o.z = (float)tl[(d16 + q * 4 + 2) * 136 + n];
            o.w = (float)tl[(d16 + q * 4 + 3) * 136 + n];
            *(float4*)(op + q * 4) = o;
        }
    }
}

// ---------------------------------------------------------------------------
extern "C" void kernel_launch(void* const* d_in, const int* in_sizes, int n_in,
                              void* d_out, int out_size, void* d_ws, size_t ws_size,
                              hipStream_t stream)
{
    const float* x    = (const float*)d_in[0];
    const float* q_w  = (const float*)d_in[1];
    const float* k_w  = (const float*)d_in[2];
    const float* v_w  = (const float*)d_in[3];
    const float* pw   = (const float*)d_in[4];
    const float* pb   = (const float*)d_in[5];
    const float* bn_q = (const float*)d_in[6];
    const float* bn_k = (const float*)d_in[7];
    const float* bn_v = (const float*)d_in[8];
    const float* bn_p = (const float*)d_in[9];

    char* ws = (char*)d_ws;
    bf16_t* xsT  = (bf16_t*)(ws);                                 // 64 MiB (reused as y3T)
    bf16_t* vc   = (bf16_t*)(ws + ((size_t)64 << 20));            // 64 MiB
    bf16_t* ahi  = (bf16_t*)(ws + ((size_t)128 << 20));           // 1 MiB
    bf16_t* alo  = (bf16_t*)(ws + ((size_t)129 << 20));           // 1 MiB
    bf16_t* wspq = (bf16_t*)(ws + ((size_t)130 << 20));           // 4 x 384 KiB
    bf16_t* wspk = wspq + 3 * 65536;
    bf16_t* wspv = wspk + 3 * 65536;
    bf16_t* wspp = wspv + 3 * 65536;
    bf16_t* y3T  = xsT;                                           // reuse after v-branch

    float* outf = (float*)d_out;
    bf16_t* qT = (bf16_t*)d_out;                                  // scratch in out0 half
    bf16_t* kc = (bf16_t*)((char*)d_out + ((size_t)64 << 20));    // scratch in out0 half

    k0_split<<<dim3(64), 256, 0, stream>>>(q_w, wspq, wspq + 65536, wspq + 131072);
    k0_split<<<dim3(64), 256, 0, stream>>>(k_w, wspk, wspk + 65536, wspk + 131072);
    k0_split<<<dim3(64), 256, 0, stream>>>(v_w, wspv, wspv + 65536, wspv + 131072);
    k0_split<<<dim3(64), 256, 0, stream>>>(pw,  wspp, wspp + 65536, wspp + 131072);

    k1_lif_tr   <<<dim3(16, 4, 16),  256, 0, stream>>>(x, xsT);
    k_branch<1> <<<dim3(16, 4, 16),  256, 0, stream>>>(wspq, bn_q, xsT, qT, 1.0f);
    k_branch<0> <<<dim3(16, 4, 16),  256, 0, stream>>>(wspk, bn_k, xsT, kc, 1.0f);
    k_branch<0> <<<dim3(16, 4, 16),  256, 0, stream>>>(wspv, bn_v, xsT, vc, 1.0f);
    k_attn      <<<dim3(512),         64, 0, stream>>>(vc, kc, ahi, alo);
    k_attn_out  <<<dim3(16, 4, 16),  256, 0, stream>>>(qT, ahi, alo, y3T);
    k_proj      <<<dim3(16, 4, 16),  256, 0, stream>>>(wspp, pb, bn_p, y3T, x, outf);
    k_vout      <<<dim3(8, 1024),    256, 0, stream>>>(vc, outf + (size_t)33554432);
}